// Round 11
// baseline (154.956 us; speedup 1.0000x reference)
//
#include <hip/hip_runtime.h>
#include <hip/hip_bf16.h>

typedef __attribute__((ext_vector_type(4))) float f32x4;
typedef __attribute__((ext_vector_type(4))) unsigned int u32x4;
typedef __attribute__((ext_vector_type(8))) short bf16x8;

__device__ __forceinline__ short f2bf(float f) {
  __hip_bfloat16 h = __float2bfloat16(f);
  return __builtin_bit_cast(short, h);
}

// Counted vmcnt + scheduling fence (rule #18: sched_barrier right after the
// waitcnt keeps register-only MFMAs from hoisting above it).
#define WAITV(N)                                            \
  {                                                         \
    asm volatile("s_waitcnt vmcnt(" #N ")" ::: "memory");   \
    __builtin_amdgcn_sched_barrier(0);                      \
  }

// ---------------------------------------------------------------------------
// GEMM view: C[8192 x 512] = A[8192 x 1024] * B[1024 x 512], k = j*4 + kc,
// kc -> x component {0,1,2,4}.  512 cols = [c0 of i=0..255 | c4 of i=0..255].
// Halved-B (R8, verified): c0 frag per j = [w0,w1,w2,0]; c4 frag =
// [0,w2,-w1,w0] built in-register. Bp stores only the c0 half (512 KB).
// R9 lesson (VGPR_Count=32): plain C loads let the compiler COLLAPSE the
// depth-4 register pipeline -> full L3 latency exposed per iter. This round
// pins it with volatile asm global_load_dwordx4 (flat 64b vaddr form) +
// counted vmcnt.
// ---------------------------------------------------------------------------
__global__ __launch_bounds__(256) void ga_prep_B(const float* __restrict__ W,
                                                 short* __restrict__ Bp) {
  const int gid = blockIdx.x * 256 + threadIdx.x;  // 32768 = 32 it * 16 cg * 64 lane
  const int l  = gid & 63;
  const int cg = (gid >> 6) & 15;
  const int it = gid >> 10;
  const int ln = l & 15, q = l >> 4;
  const int i  = cg * 16 + ln;
  const int j0 = it * 8 + q * 2;
  const float4* W4 = (const float4*)W;

  bf16x8 o;
#pragma unroll
  for (int jj = 0; jj < 2; ++jj) {
    const float4 wv = W4[((j0 + jj) * 256 + i) * 2];  // W[j][i][0..3]
    o[jj * 4 + 0] = f2bf(wv.x); o[jj * 4 + 1] = f2bf(wv.y);
    o[jj * 4 + 2] = f2bf(wv.z); o[jj * 4 + 3] = 0;
  }
  *(bf16x8*)&Bp[(size_t)gid * 8] = o;
}

// ---------------------------------------------------------------------------
// prep_A: x (f32, 67MB) -> frag-ready bf16 A image (16.8MB, L3-resident).
// A[row][j][comp4 {0,1,2,4}] bf16, row stride 1024 shorts; MFMA A-frag for
// lane (ln,qq), k-slice it = contiguous 16B at row*1024 + it*32 + qq*8.
// Confirmed ~6.2 TB/s shape (R9 totals).
// ---------------------------------------------------------------------------
__global__ __launch_bounds__(256) void ga_prep_A(const float* __restrict__ x,
                                                 short* __restrict__ A) {
  const int g = blockIdx.x * 256 + threadIdx.x;  // 1,048,576 = 8192 rows * 128 jp
  const float4* xp = (const float4*)x + (size_t)g * 4;
  const float4 a0 = xp[0], a1 = xp[1], b0 = xp[2], b1 = xp[3];
  bf16x8 o;
  o[0] = f2bf(a0.x); o[1] = f2bf(a0.y); o[2] = f2bf(a0.z); o[3] = f2bf(a1.x);
  o[4] = f2bf(b0.x); o[5] = f2bf(b0.y); o[6] = f2bf(b0.z); o[7] = f2bf(b1.x);
  *(bf16x8*)&A[(size_t)g * 8] = o;
}

// ---------------------------------------------------------------------------
// gemm: 2048 blocks x 256 threads (4 waves), 0 LDS, 0 barriers.
// Grid remap: bids {b, b+8, b+16, b+24} share one A-tile AND one XCD
// (round-robin dispatch) -> A-tile L2 reuse. Wave = 16 rows x col-group cg.
// K-loop: depth-4 register pipeline held by VOLATILE ASM loads (program
// order fixed, "memory" clobbers keep C loads out of the FIFO window):
// pair(it) = {A-frag: fixed 64b vaddr + offset:it*64 imm; B-frag: 64b vaddr
// advanced 16384 B per issue}. Steady-state WAITV(6) = 3 pairs in flight;
// drain 6/4/2/0.  ~16 waves/CU x independent phases cover ~500cy L3 latency.
// Epilogue: direct per-lane full-multivector nontemporal stores.
// ---------------------------------------------------------------------------
__global__ __launch_bounds__(256, 4) void ga_gemm(
    const short* __restrict__ A, const short* __restrict__ Bp,
    const float* __restrict__ bias, float* __restrict__ y) {
  const int t = threadIdx.x, lane = t & 63, w = t >> 6;
  const int ln = lane & 15, qq = lane >> 4;
  const int bid = blockIdx.x;
  const int bm = (bid & 7) | ((bid >> 5) << 3);  // A-tile sharers -> same XCD
  const int cb = (bid >> 3) & 3;
  const int R0 = bm * 16, cg = cb * 4 + w;
  const int i = cg * 16 + ln;  // output col (c0) / +256 (c4)

  // Per-lane 64-bit addresses (flat-vaddr form: global_load v[d], v[a:a+1], off)
  const short* apL = A + (size_t)(R0 + ln) * 1024 + qq * 8;  // + it*64 B imm
  const short* bpL = Bp + (size_t)cg * 512 + lane * 8;       // += 16384 B/issue

  bf16x8 Af[4], Bf[4];

#define GLA(slot, IMM)                                               \
  asm volatile("global_load_dwordx4 %0, %1, off offset:" #IMM        \
               : "=&v"(Af[slot])                                     \
               : "v"(apL)                                            \
               : "memory");
#define GLB(slot)                                                    \
  {                                                                  \
    asm volatile("global_load_dwordx4 %0, %1, off"                   \
                 : "=&v"(Bf[slot])                                   \
                 : "v"(bpL)                                          \
                 : "memory");                                        \
    bpL += 8192; /* 16384 B to next k-slice */                       \
  }
#define PAIR(slot, IMM) { GLA(slot, IMM) GLB(slot) }

  // prologue: 4 pairs in flight (8 loads)
  PAIR(0, 0) PAIR(1, 64) PAIR(2, 128) PAIR(3, 192)

  f32x4 acc0 = {}, acc1 = {};

#define ITER(it, N, IMM)                                                      \
  {                                                                           \
    WAITV(N);                                                                 \
    const bf16x8 af = Af[(it) & 3];                                           \
    const bf16x8 F = Bf[(it) & 3];                                            \
    const u32x4 fu = __builtin_bit_cast(u32x4, F);                            \
    u32x4 gu;                                                                 \
    gu.x = fu.y << 16;                               /* [0, w2]   */          \
    gu.y = ((fu.x >> 16) | (fu.x << 16)) ^ 0x8000u;  /* [-w1, w0] */          \
    gu.z = fu.w << 16;                                                        \
    gu.w = ((fu.z >> 16) | (fu.z << 16)) ^ 0x8000u;                           \
    const bf16x8 G = __builtin_bit_cast(bf16x8, gu);                          \
    acc0 = __builtin_amdgcn_mfma_f32_16x16x32_bf16(af, F, acc0, 0, 0, 0);     \
    acc1 = __builtin_amdgcn_mfma_f32_16x16x32_bf16(af, G, acc1, 0, 0, 0);     \
    if ((it) + 4 < 32) PAIR((it) & 3, IMM)                                    \
  }

  ITER(0, 6, 256)   ITER(1, 6, 320)   ITER(2, 6, 384)   ITER(3, 6, 448)
  ITER(4, 6, 512)   ITER(5, 6, 576)   ITER(6, 6, 640)   ITER(7, 6, 704)
  ITER(8, 6, 768)   ITER(9, 6, 832)   ITER(10, 6, 896)  ITER(11, 6, 960)
  ITER(12, 6, 1024) ITER(13, 6, 1088) ITER(14, 6, 1152) ITER(15, 6, 1216)
  ITER(16, 6, 1280) ITER(17, 6, 1344) ITER(18, 6, 1408) ITER(19, 6, 1472)
  ITER(20, 6, 1536) ITER(21, 6, 1600) ITER(22, 6, 1664) ITER(23, 6, 1728)
  ITER(24, 6, 1792) ITER(25, 6, 1856) ITER(26, 6, 1920) ITER(27, 6, 1984)
  ITER(28, 6, 0)    ITER(29, 4, 0)    ITER(30, 2, 0)    ITER(31, 0, 0)

  // ---- epilogue: C/D layout col = ln, row = qq*4 + r (verified R9) ----
  const f32x4 bv0 = ((const f32x4*)bias)[i * 2];      // bias[i][0..3]
  const f32x4 bv1 = ((const f32x4*)bias)[i * 2 + 1];  // bias[i][4..7]
  f32x4* yp = (f32x4*)y + ((size_t)(R0 + qq * 4) * 256 + i) * 2;
#pragma unroll
  for (int r = 0; r < 4; ++r) {
    f32x4 o0 = bv0, o1 = bv1;
    o0[0] += acc0[r];  // c0 -> comp 0
    o1[0] += acc1[r];  // c4 -> comp 4
    __builtin_nontemporal_store(o0, yp + (size_t)r * 512);
    __builtin_nontemporal_store(o1, yp + (size_t)r * 512 + 1);
  }
}

extern "C" void kernel_launch(void* const* d_in, const int* in_sizes, int n_in,
                              void* d_out, int out_size, void* d_ws, size_t ws_size,
                              hipStream_t stream) {
  const float* x = (const float*)d_in[0];
  const float* W = (const float*)d_in[1];
  const float* bias = (const float*)d_in[2];
  float* y = (float*)d_out;
  short* Bp = (short*)d_ws;                  // 512 KB (c0 half only)
  short* A = (short*)d_ws + (1 << 18);       // 16.8 MB bf16 A image

  ga_prep_B<<<dim3(128), dim3(256), 0, stream>>>(W, Bp);
  ga_prep_A<<<dim3(4096), dim3(256), 0, stream>>>(x, A);
  ga_gemm<<<dim3(2048), dim3(256), 0, stream>>>(A, Bp, bias, y);
}

// Round 12
// 128.769 us; speedup vs baseline: 1.2034x; 1.2034x over previous
//
#include <hip/hip_runtime.h>
#include <hip/hip_bf16.h>

typedef __attribute__((ext_vector_type(4))) float f32x4;
typedef __attribute__((ext_vector_type(4))) unsigned int u32x4;
typedef __attribute__((ext_vector_type(8))) short bf16x8;

#define CS 516  // dwords per epilogue c row (512 + 4 pad)

__device__ __forceinline__ short f2bf(float f) {
  __hip_bfloat16 h = __float2bfloat16(f);
  return __builtin_bit_cast(short, h);
}

// global_load_lds width 16: wave-uniform LDS base + lane*16, per-lane gsrc.
#define GLD_LDS16(gp, lp)                                                    \
  __builtin_amdgcn_global_load_lds(                                          \
      (const __attribute__((address_space(1))) unsigned int*)(gp),           \
      (__attribute__((address_space(3))) unsigned int*)(lp), 16, 0, 0)

// lgkm-only barrier: LDS ops complete; vmcnt pipelines legally cross it.
#define QBAR()                                              \
  {                                                         \
    asm volatile("s_waitcnt lgkmcnt(0)" ::: "memory");      \
    __builtin_amdgcn_sched_barrier(0);                      \
    __builtin_amdgcn_s_barrier();                           \
    __builtin_amdgcn_sched_barrier(0);                      \
  }

// ---------------------------------------------------------------------------
// GEMM view: C[8192 x 512] = A[8192 x 1024] * B[1024 x 512], k = j*4 + kc,
// kc -> x component {0,1,2,4}.  512 cols = [c0 of i=0..255 | c4 of i=0..255].
// R12 = recombination of the two best-measured engines:
//   - R4's split main (A-image via global_load_lds, 11 TB/s aggregate)
//   - R8's halved-B (c4 frag = [0,w2,-w1,w0] built in-register; Bp = 512 KB)
// ---------------------------------------------------------------------------
__global__ __launch_bounds__(256) void ga_prep_B(const float* __restrict__ W,
                                                 short* __restrict__ Bp) {
  const int gid = blockIdx.x * 256 + threadIdx.x;  // 32768 = 32 it * 16 cg * 64 lane
  const int l  = gid & 63;
  const int cg = (gid >> 6) & 15;
  const int it = gid >> 10;
  const int ln = l & 15, q = l >> 4;
  const int i  = cg * 16 + ln;
  const int j0 = it * 8 + q * 2;
  const float4* W4 = (const float4*)W;

  bf16x8 o;
#pragma unroll
  for (int jj = 0; jj < 2; ++jj) {
    const float4 wv = W4[((j0 + jj) * 256 + i) * 2];  // W[j][i][0..3]
    o[jj * 4 + 0] = f2bf(wv.x); o[jj * 4 + 1] = f2bf(wv.y);
    o[jj * 4 + 2] = f2bf(wv.z); o[jj * 4 + 3] = 0;
  }
  *(bf16x8*)&Bp[(size_t)gid * 8] = o;
}

// ---------------------------------------------------------------------------
// prep_A (R4-verified, ~6.3 TB/s): x (f32, 67MB) -> bf16 A image (16.8MB,
// L3-resident). Granule (row, chunk c) = 16 B = 8 k-elems (j pair x comps
// {0,1,2,4}), stored at c' = c ^ ((row&7)<<2) so main's linear
// global_load_lds + swizzled ds_read works. A[row 8192][q 4][c' 32].
// ---------------------------------------------------------------------------
__global__ __launch_bounds__(256) void ga_prep_A(const float* __restrict__ x,
                                                 short* __restrict__ A) {
  const int g = blockIdx.x * 256 + threadIdx.x;  // 1,048,576 granules
  const int row = g >> 7, rem = g & 127;
  const int q = rem >> 5, c = rem & 31;
  const int cp = c ^ ((row & 7) << 2);
  const float4* x4 = (const float4*)x + (size_t)(row * 256 + q * 64 + c * 2) * 2;
  const float4 a0 = x4[0], a1 = x4[1], b0 = x4[2], b1 = x4[3];
  bf16x8 o;
  o[0] = f2bf(a0.x); o[1] = f2bf(a0.y); o[2] = f2bf(a0.z); o[3] = f2bf(a1.x);
  o[4] = f2bf(b0.x); o[5] = f2bf(b0.y); o[6] = f2bf(b0.z); o[7] = f2bf(b1.x);
  *(bf16x8*)&A[((size_t)row * 128 + q * 32 + cp) * 8] = o;
}

// ---------------------------------------------------------------------------
// Main (R4 body + R8 halved-B): 256 blocks (32 rows x ALL 512 cols) x 1024
// threads (16 waves). Prologue: stage this block's 64KB A via 4x
// global_load_lds(16B)/thread + 4 B-frag batches, ONE __syncthreads.
// K-loop: 32 iters, BARRIER-FREE: 2 ds_read_b128 (swizzle-spread) + build
// c4 G-frag in-register (6 VALU) + 4 MFMA + depth-4 B reg pipeline (wave w
// owns cg w -> 32KB B per wave, 128MB aggregate vs R4's 256MB).
// Epilogue: two 16-row passes via c_lds alias, nontemporal full-mv writes.
// ---------------------------------------------------------------------------
__global__ __launch_bounds__(1024, 4) void ga_mv_main(
    const short* __restrict__ A, const short* __restrict__ Bp,
    const float* __restrict__ bias, float* __restrict__ y) {
  __shared__ __align__(16) char smem[65536];
  short* lds_s = (short*)smem;
  float* c_lds = (float*)smem;  // epilogue alias (A dead by then): 33024 B

  const int t = threadIdx.x;
  const int bm = blockIdx.x;  // 256 blocks x 32 rows
  const int lane = t & 63, w = t >> 6;
  const int ln = lane & 15, qq = lane >> 4, lnl = lane & 7;
  const int R0 = bm * 32;

  // ---- stage A: thread t copies granule (row = t>>5, c' = t&31), each q ----
  const short* asrc = A + ((size_t)(R0 + (t >> 5)) * 128 + (t & 31)) * 8;
#pragma unroll
  for (int q = 0; q < 4; ++q)
    GLD_LDS16(asrc + q * 256, lds_s + q * 8192 + t * 8);

  // ---- B frag pipeline (depth 4). Wave w owns cg w (halved Bp):
  // slice it at Bp + it*8192 shorts; wave offset w*512 + lane*8.
  const size_t bbase = (size_t)w * 512 + lane * 8;
  bf16x8 Bf[4];
#define LB(itv, b) { Bf[b] = *(const bf16x8*)(Bp + (size_t)(itv) * 8192 + bbase); }
  LB(0, 0);
  LB(1, 1);
  LB(2, 2);
  LB(3, 3);

  __syncthreads();  // one-time drain: A staged + prologue B in regs

  // ---- K loop: barrier-free ----
  f32x4 acc[2][2] = {};  // [row-half][F/G]
  const int abase = ln * 256 + qq * 8;  // shorts
#pragma unroll
  for (int it = 0; it < 32; ++it) {
    const int q = it >> 3, tau = it & 7;
    const short* Aq = lds_s + q * 8192 + abase + ((tau ^ lnl) << 5);
    const bf16x8 af0 = *(const bf16x8*)Aq;           // rows 0-15
    const bf16x8 af1 = *(const bf16x8*)(Aq + 4096);  // rows 16-31
    const bf16x8 F = Bf[it & 3];
    const u32x4 fu = __builtin_bit_cast(u32x4, F);
    u32x4 gu;
    gu.x = fu.y << 16;                               // [0, w2]
    gu.y = ((fu.x >> 16) | (fu.x << 16)) ^ 0x8000u;  // [-w1, w0]
    gu.z = fu.w << 16;
    gu.w = ((fu.z >> 16) | (fu.z << 16)) ^ 0x8000u;
    const bf16x8 G = __builtin_bit_cast(bf16x8, gu);
    acc[0][0] = __builtin_amdgcn_mfma_f32_16x16x32_bf16(af0, F, acc[0][0], 0, 0, 0);
    acc[1][0] = __builtin_amdgcn_mfma_f32_16x16x32_bf16(af1, F, acc[1][0], 0, 0, 0);
    acc[0][1] = __builtin_amdgcn_mfma_f32_16x16x32_bf16(af0, G, acc[0][1], 0, 0, 0);
    acc[1][1] = __builtin_amdgcn_mfma_f32_16x16x32_bf16(af1, G, acc[1][1], 0, 0, 0);
    if (it + 4 < 32) LB(it + 4, it & 3);  // after use of Bf[it&3] (WAR-safe)
  }
  QBAR();  // all A reads done before c_lds alias writes

  // ---- epilogue (R8-verified): two 16-row passes; wave w cols:
  // n=0 -> c0 col 16w+ln, n=1 -> c4 col 256+16w+ln.
  // C/D layout: col = ln, row(within 16-tile) = qq*4 + r.
  const int h = t & 1, p = (t >> 1) & 255, rh = t >> 9;
  const float4 bv = ((const float4*)bias)[p * 2 + h];
  f32x4* y4 = (f32x4*)y;

#pragma unroll
  for (int ep = 0; ep < 2; ++ep) {
    if (ep) QBAR();  // pass-0 c_lds reads done before pass-1 writes
#pragma unroll
    for (int n = 0; n < 2; ++n)
#pragma unroll
      for (int r = 0; r < 4; ++r)
        c_lds[(qq * 4 + r) * CS + n * 256 + w * 16 + ln] = acc[ep][n][r];
    QBAR();  // all waves' c_lds writes visible
#pragma unroll
    for (int rr = 0; rr < 8; ++rr) {
      const int row = rr * 2 + rh;
      f32x4 o;
      o[0] = bv.x; o[1] = bv.y; o[2] = bv.z; o[3] = bv.w;
      o[0] += c_lds[row * CS + h * 256 + p];  // +c0 into comp0 / +c4 into comp4
      __builtin_nontemporal_store(
          o, &y4[((size_t)(R0 + ep * 16 + row) * 256 + p) * 2 + h]);
    }
  }
}

extern "C" void kernel_launch(void* const* d_in, const int* in_sizes, int n_in,
                              void* d_out, int out_size, void* d_ws, size_t ws_size,
                              hipStream_t stream) {
  const float* x = (const float*)d_in[0];
  const float* W = (const float*)d_in[1];
  const float* bias = (const float*)d_in[2];
  float* y = (float*)d_out;
  short* Bp = (short*)d_ws;                 // 512 KB (c0 half only)
  short* A = (short*)d_ws + (1 << 18);      // 16.8 MB bf16 A image

  ga_prep_B<<<dim3(128), dim3(256), 0, stream>>>(W, Bp);
  ga_prep_A<<<dim3(4096), dim3(256), 0, stream>>>(x, A);
  ga_mv_main<<<dim3(256), dim3(1024), 0, stream>>>(A, Bp, bias, y);
}